// Round 1
// baseline (748.564 us; speedup 1.0000x reference)
//
#include <hip/hip_runtime.h>
#include <hip/hip_fp16.h>
#include <math.h>

#define T_LEN 8192
#define HALF_T 4096
#define CHN 128
#define BATCH 16
#define NKCHUNK 8
#define KCHUNK 1024

// One block per (b,c) row: 8192-pt FFT -> mask upper half -> IFFT -> normalize
// to unit modulus (== cos/sin of the phase), store as half2.
__global__ __launch_bounds__(256) void fft_analytic_kernel(const float* __restrict__ x,
                                                           __half2* __restrict__ z) {
    __shared__ float2 buf[T_LEN];   // 64 KiB
    const int tid = threadIdx.x;
    const size_t row = blockIdx.x;
    const float* xr = x + row * (size_t)T_LEN;

    for (int t = tid; t < T_LEN; t += 256)
        buf[t] = make_float2(xr[t], 0.0f);
    __syncthreads();

    // Forward radix-2 DIF: natural order in, bit-reversed out. Twiddle e^{-i*pi*j/m}.
    for (int m = HALF_T; m >= 1; m >>= 1) {
        const float ascale = -(float)M_PI / (float)m;
        for (int idx = tid; idx < HALF_T; idx += 256) {
            const int j  = idx & (m - 1);
            const int i1 = ((idx & ~(m - 1)) << 1) | j;
            const int i2 = i1 + m;
            float2 a = buf[i1];
            float2 b = buf[i2];
            float s, c;
            __sincosf(ascale * (float)j, &s, &c);
            const float dx = a.x - b.x, dy = a.y - b.y;
            buf[i1] = make_float2(a.x + b.x, a.y + b.y);
            buf[i2] = make_float2(dx * c - dy * s, dx * s + dy * c);
        }
        __syncthreads();
    }

    // Position p holds frequency k = bitrev13(p). Keep k < T/2 <=> bit12(k)=0 <=> p even.
    for (int p = tid; p < T_LEN; p += 256)
        if (p & 1) buf[p] = make_float2(0.0f, 0.0f);
    __syncthreads();

    // Inverse radix-2 DIT: bit-reversed in, natural out. Twiddle e^{+i*pi*j/m}.
    // 1/N scale omitted (cancels under normalization).
    for (int m = 1; m <= HALF_T; m <<= 1) {
        const float ascale = (float)M_PI / (float)m;
        for (int idx = tid; idx < HALF_T; idx += 256) {
            const int j  = idx & (m - 1);
            const int i1 = ((idx & ~(m - 1)) << 1) | j;
            const int i2 = i1 + m;
            float2 a = buf[i1];
            float2 b = buf[i2];
            float s, c;
            __sincosf(ascale * (float)j, &s, &c);
            const float bx = b.x * c - b.y * s;
            const float by = b.x * s + b.y * c;
            buf[i1] = make_float2(a.x + bx, a.y + by);
            buf[i2] = make_float2(a.x - bx, a.y - by);
        }
        __syncthreads();
    }

    // z = xa / |xa|  (cos(phase), sin(phase)); atan2(0,0)=0 -> (1,0).
    __half2* zr = z + row * (size_t)T_LEN;
    for (int t = tid; t < T_LEN; t += 256) {
        float2 v = buf[t];
        float n2 = v.x * v.x + v.y * v.y;
        float ux, uy;
        if (n2 > 0.0f) {
            float inv = rsqrtf(n2);
            ux = v.x * inv; uy = v.y * inv;
        } else {
            ux = 1.0f; uy = 0.0f;
        }
        zr[t] = __floats2half2_rn(ux, uy);
    }
}

// Per-batch complex Gram partials: G[b][i][j] += sum_t z_i(t)*conj(z_j(t)).
// grid = (BATCH, 4 tiles of 64x64, NKCHUNK k-chunks), block = 256 (16x16, 4x4 outputs each)
__global__ __launch_bounds__(256) void gram_kernel(const __half2* __restrict__ z,
                                                   float2* __restrict__ partial) {
    const int b    = blockIdx.x;
    const int tile = blockIdx.y;
    const int kc   = blockIdx.z;
    const int ti = (tile >> 1) * 64;
    const int tj = (tile & 1) * 64;
    const int tx = threadIdx.x & 15;
    const int ty = threadIdx.x >> 4;

    __shared__ float2 sa[64][33];   // +1 float2 pad breaks bank conflicts
    __shared__ float2 sb[64][33];

    float accre[4][4] = {};
    float accim[4][4] = {};

    const __half2* zb = z + (size_t)b * CHN * T_LEN;
    const int k0 = kc * KCHUNK;

    for (int ks = 0; ks < KCHUNK; ks += 32) {
        for (int l = threadIdx.x; l < 64 * 32; l += 256) {
            const int r = l >> 5;
            const int cpos = l & 31;
            const size_t col = (size_t)(k0 + ks + cpos);
            sa[r][cpos] = __half22float2(zb[(size_t)(ti + r) * T_LEN + col]);
            sb[r][cpos] = __half22float2(zb[(size_t)(tj + r) * T_LEN + col]);
        }
        __syncthreads();
#pragma unroll 8
        for (int kk = 0; kk < 32; ++kk) {
            float2 av[4], bv[4];
#pragma unroll
            for (int u = 0; u < 4; ++u) av[u] = sa[ty * 4 + u][kk];
#pragma unroll
            for (int v = 0; v < 4; ++v) bv[v] = sb[tx * 4 + v][kk];
#pragma unroll
            for (int u = 0; u < 4; ++u)
#pragma unroll
                for (int v = 0; v < 4; ++v) {
                    // z_i * conj(z_j)
                    accre[u][v] += av[u].x * bv[v].x + av[u].y * bv[v].y;
                    accim[u][v] += av[u].y * bv[v].x - av[u].x * bv[v].y;
                }
        }
        __syncthreads();
    }

    float2* pb = partial + ((size_t)kc * BATCH + b) * CHN * CHN;
#pragma unroll
    for (int u = 0; u < 4; ++u)
#pragma unroll
        for (int v = 0; v < 4; ++v) {
            const int i = ti + ty * 4 + u;
            const int j = tj + tx * 4 + v;
            pb[(size_t)i * CHN + j] = make_float2(accre[u][v], accim[u][v]);
        }
}

__global__ __launch_bounds__(256) void reduce_kernel(const float2* __restrict__ partial,
                                                     float* __restrict__ out) {
    const size_t i = (size_t)blockIdx.x * 256 + threadIdx.x;
    const size_t n = (size_t)BATCH * CHN * CHN;
    if (i >= n) return;
    float re = 0.0f, im = 0.0f;
#pragma unroll
    for (int c = 0; c < NKCHUNK; ++c) {
        float2 p = partial[(size_t)c * n + i];
        re += p.x;
        im += p.y;
    }
    out[i] = sqrtf(re * re + im * im) * (1.0f / (float)T_LEN);
}

extern "C" void kernel_launch(void* const* d_in, const int* in_sizes, int n_in,
                              void* d_out, int out_size, void* d_ws, size_t ws_size,
                              hipStream_t stream) {
    const float* x = (const float*)d_in[0];
    float* out = (float*)d_out;

    __half2* z = (__half2*)d_ws;
    const size_t z_bytes = (size_t)BATCH * CHN * T_LEN * sizeof(__half2);  // 64 MiB
    float2* partial = (float2*)((char*)d_ws + z_bytes);                    // +16 MiB

    fft_analytic_kernel<<<BATCH * CHN, 256, 0, stream>>>(x, z);

    dim3 g2(BATCH, 4, NKCHUNK);
    gram_kernel<<<g2, 256, 0, stream>>>(z, partial);

    const int n_out = BATCH * CHN * CHN;
    reduce_kernel<<<(n_out + 255) / 256, 256, 0, stream>>>(partial, out);
}

// Round 2
// 235.408 us; speedup vs baseline: 3.1799x; 3.1799x over previous
//
#include <hip/hip_runtime.h>
#include <math.h>

#define T_LEN 8192
#define CHN 128
#define BATCH 16
#define NKCHUNK 8

typedef short bf16x8 __attribute__((ext_vector_type(8)));
typedef float f32x16 __attribute__((ext_vector_type(16)));

__device__ __forceinline__ ushort f2bf(float f) {
    // round-to-nearest-even float32 -> bf16 (inputs are finite, in [-1,1])
    unsigned u = __float_as_uint(f);
    unsigned r = (u + 0x7fffu + ((u >> 16) & 1u)) >> 16;
    return (ushort)r;
}

// One block per (b,c) row: radix-4 FFT -> fused mask+m=1 stages -> radix-4 IFFT
// -> normalize to unit modulus -> store cos/sin planes as bf16.
__global__ __launch_bounds__(256) void fft_analytic_kernel(const float* __restrict__ x,
                                                           ushort* __restrict__ zc,
                                                           ushort* __restrict__ zs) {
    __shared__ __align__(16) float2 buf[T_LEN];   // 64 KiB
    const int tid = threadIdx.x;
    const size_t row = blockIdx.x;
    const float* xr = x + (row << 13);

    // load (float4 per lane, lane-contiguous)
    for (int s = 0; s < 8; ++s) {
        int idx = tid + (s << 8);                 // float4 index, 2048 total
        float4 v = *(const float4*)(xr + idx * 4);
        *(float4*)&buf[idx * 4]     = make_float4(v.x, 0.f, v.y, 0.f);
        *(float4*)&buf[idx * 4 + 2] = make_float4(v.z, 0.f, v.w, 0.f);
    }
    __syncthreads();

    // forward radix-4 DIF (== composed radix-2 stages m=4Q/2..2), natural -> digit-reversed
    for (int Q = 2048; Q >= 2; Q >>= 2) {
        const float astep = -(float)M_PI / (float)(2 * Q);
        for (int s = 0; s < 8; ++s) {
            int g = tid + (s << 8);
            int j = g & (Q - 1);
            int i = ((g & ~(Q - 1)) << 2) | j;
            float2 x0 = buf[i], x1 = buf[i + Q], x2 = buf[i + 2 * Q], x3 = buf[i + 3 * Q];
            float sn, cs;
            __sincosf(astep * (float)j, &sn, &cs);
            const float w2x = cs * cs - sn * sn, w2y = 2.f * cs * sn;
            const float w3x = w2x * cs - w2y * sn, w3y = w2x * sn + w2y * cs;
            const float t0x = x0.x + x2.x, t0y = x0.y + x2.y;
            const float t1x = x0.x - x2.x, t1y = x0.y - x2.y;
            const float t2x = x1.x + x3.x, t2y = x1.y + x3.y;
            const float t3x = x1.x - x3.x, t3y = x1.y - x3.y;
            buf[i] = make_float2(t0x + t2x, t0y + t2y);
            const float d1x = t0x - t2x, d1y = t0y - t2y;
            buf[i + Q] = make_float2(d1x * w2x - d1y * w2y, d1x * w2y + d1y * w2x);
            const float d2x = t1x + t3y, d2y = t1y - t3x;        // (x0-x2) - i(x1-x3)
            buf[i + 2 * Q] = make_float2(d2x * cs - d2y * sn, d2x * sn + d2y * cs);
            const float d3x = t1x - t3y, d3y = t1y + t3x;        // (x0-x2) + i(x1-x3)
            buf[i + 3 * Q] = make_float2(d3x * w3x - d3y * w3y, d3x * w3y + d3y * w3x);
        }
        __syncthreads();
    }

    // fused: fwd m=1 stage + zero-odd-positions mask + inv m=1 stage
    // S_even=e+o, S_odd=0  =>  x_even = x_odd = e+o
    for (int s = 0; s < 16; ++s) {
        int q = tid + (s << 8);                   // pair index 0..4095
        float4 eo = *(const float4*)&buf[q * 2];
        float sx = eo.x + eo.z, sy = eo.y + eo.w;
        *(float4*)&buf[q * 2] = make_float4(sx, sy, sx, sy);
    }
    __syncthreads();

    // inverse radix-4 DIT, digit-reversed -> natural (1/N scale omitted; cancels below)
    for (int Q = 2; Q <= 2048; Q <<= 2) {
        const float astep = (float)M_PI / (float)(2 * Q);
        for (int s = 0; s < 8; ++s) {
            int g = tid + (s << 8);
            int j = g & (Q - 1);
            int i = ((g & ~(Q - 1)) << 2) | j;
            float2 v0 = buf[i], v1 = buf[i + Q], v2 = buf[i + 2 * Q], v3 = buf[i + 3 * Q];
            float sn, cs;
            __sincosf(astep * (float)j, &sn, &cs);
            const float w2x = cs * cs - sn * sn, w2y = 2.f * cs * sn;
            const float w3x = w2x * cs - w2y * sn, w3y = w2x * sn + w2y * cs;
            const float a1x = v1.x * w2x - v1.y * w2y, a1y = v1.x * w2y + v1.y * w2x;  // v1*W^2
            const float a2x = v2.x * cs - v2.y * sn,  a2y = v2.x * sn + v2.y * cs;     // v2*W
            const float a3x = v3.x * w3x - v3.y * w3y, a3y = v3.x * w3y + v3.y * w3x;  // v3*W^3
            const float u0x = v0.x + a1x, u0y = v0.y + a1y;
            const float u1x = v0.x - a1x, u1y = v0.y - a1y;
            const float px = a2x + a3x, py = a2y + a3y;          // w2+w3
            const float mx = -(a2y - a3y), my = a2x - a3x;       // i*(w2-w3)
            buf[i]         = make_float2(u0x + px, u0y + py);
            buf[i + 2 * Q] = make_float2(u0x - px, u0y - py);
            buf[i + Q]     = make_float2(u1x + mx, u1y + my);
            buf[i + 3 * Q] = make_float2(u1x - mx, u1y - my);
        }
        __syncthreads();
    }

    // normalize to unit modulus: (cos(phase), sin(phase)); (0,0) -> (1,0)
    ushort* zcr = zc + (row << 13);
    ushort* zsr = zs + (row << 13);
    for (int s = 0; s < 16; ++s) {
        int tt = tid + (s << 8);                  // 0..4095, handles elements 2tt, 2tt+1
        float4 two = *(const float4*)&buf[tt * 2];
        float n0 = two.x * two.x + two.y * two.y;
        float n1 = two.z * two.z + two.w * two.w;
        float c0 = 1.f, s0 = 0.f, c1 = 1.f, s1 = 0.f;
        if (n0 > 0.f) { float inv = rsqrtf(n0); c0 = two.x * inv; s0 = two.y * inv; }
        if (n1 > 0.f) { float inv = rsqrtf(n1); c1 = two.z * inv; s1 = two.w * inv; }
        ushort2 pc = make_ushort2(f2bf(c0), f2bf(c1));
        ushort2 ps = make_ushort2(f2bf(s0), f2bf(s1));
        *(ushort2*)&zcr[tt * 2] = pc;
        *(ushort2*)&zsr[tt * 2] = ps;
    }
}

// MFMA Gram partials. grid=(BATCH, 2 col-halves, NKCHUNK), block=256 (4 waves).
// Block computes G[b][0:128][j0:j0+64] over t in [kc*1024, kc*1024+1024).
// re = C_i C_j + S_i S_j ; im = S_i C_j + (-C_i) S_j.
__global__ __launch_bounds__(256) void gram_kernel(const ushort* __restrict__ zc,
                                                   const ushort* __restrict__ zs,
                                                   float2* __restrict__ partial) {
    const int b = blockIdx.x, jh = blockIdx.y, kc = blockIdx.z;
    const int j0 = jh * 64;
    const int tid = threadIdx.x;
    const int wave = tid >> 6;
    const int lane31 = tid & 31;
    const int half = (tid >> 5) & 1;

    __shared__ __align__(16) ushort sZ[2][128 * 40];   // stride 40 bf16 = 80 B (16B-aligned pad)

    f32x16 accRe[2], accIm[2];
#pragma unroll
    for (int v = 0; v < 2; ++v)
#pragma unroll
        for (int r = 0; r < 16; ++r) { accRe[v][r] = 0.f; accIm[v][r] = 0.f; }

    const size_t base = ((size_t)b * CHN) << 13;   // b*128*8192 (elements)
    const int k0 = kc << 10;

    for (int ks = 0; ks < 1024; ks += 32) {
        __syncthreads();
        // stage C and S tiles: 128 rows x 32 cols each, 16B chunks, 4 per thread
#pragma unroll
        for (int q = 0; q < 4; ++q) {
            int id = tid + (q << 8);               // 0..1023
            int plane = id >> 9;                   // wave-uniform per q
            int rid = (id >> 2) & 127;
            int ck = id & 3;
            const ushort* src = (plane ? zs : zc) + base + ((size_t)rid << 13)
                                + (size_t)(k0 + ks + ck * 8);
            uint4 v = *(const uint4*)src;
            *(uint4*)&sZ[plane][rid * 40 + ck * 8] = v;
        }
        __syncthreads();
#pragma unroll
        for (int kb = 0; kb < 32; kb += 16) {
            const int aoff = (wave * 32 + lane31) * 40 + kb + half * 8;
            bf16x8 aC = *(const bf16x8*)&sZ[0][aoff];
            bf16x8 aS = *(const bf16x8*)&sZ[1][aoff];
            bf16x8 aCn;
#pragma unroll
            for (int r = 0; r < 8; ++r) aCn[r] = (short)(aC[r] ^ (short)0x8000);
#pragma unroll
            for (int v = 0; v < 2; ++v) {
                const int boff = (j0 + v * 32 + lane31) * 40 + kb + half * 8;
                bf16x8 bC = *(const bf16x8*)&sZ[0][boff];
                bf16x8 bS = *(const bf16x8*)&sZ[1][boff];
                accRe[v] = __builtin_amdgcn_mfma_f32_32x32x16_bf16(aC,  bC, accRe[v], 0, 0, 0);
                accRe[v] = __builtin_amdgcn_mfma_f32_32x32x16_bf16(aS,  bS, accRe[v], 0, 0, 0);
                accIm[v] = __builtin_amdgcn_mfma_f32_32x32x16_bf16(aS,  bC, accIm[v], 0, 0, 0);
                accIm[v] = __builtin_amdgcn_mfma_f32_32x32x16_bf16(aCn, bS, accIm[v], 0, 0, 0);
            }
        }
    }

    // C/D layout (verified m74/m101): col=lane&31, row=(reg&3)+8*(reg>>2)+4*(lane>>5)
    float2* pb = partial + ((size_t)(kc * BATCH + b) << 14);
#pragma unroll
    for (int v = 0; v < 2; ++v)
#pragma unroll
        for (int r = 0; r < 16; ++r) {
            int rrow = (r & 3) + 8 * (r >> 2) + 4 * half;
            int i = wave * 32 + rrow;
            int j = j0 + v * 32 + lane31;
            pb[i * CHN + j] = make_float2(accRe[v][r], accIm[v][r]);
        }
}

__global__ __launch_bounds__(256) void reduce_kernel(const float2* __restrict__ partial,
                                                     float* __restrict__ out) {
    const size_t i = (size_t)blockIdx.x * 256 + threadIdx.x;
    const size_t n = (size_t)BATCH * CHN * CHN;
    if (i >= n) return;
    float re = 0.0f, im = 0.0f;
#pragma unroll
    for (int c = 0; c < NKCHUNK; ++c) {
        float2 p = partial[(size_t)c * n + i];
        re += p.x;
        im += p.y;
    }
    out[i] = sqrtf(re * re + im * im) * (1.0f / (float)T_LEN);
}

extern "C" void kernel_launch(void* const* d_in, const int* in_sizes, int n_in,
                              void* d_out, int out_size, void* d_ws, size_t ws_size,
                              hipStream_t stream) {
    const float* x = (const float*)d_in[0];
    float* out = (float*)d_out;

    const size_t plane_elems = (size_t)BATCH * CHN * T_LEN;          // 16.8M
    ushort* zc = (ushort*)d_ws;                                      // 33.55 MB
    ushort* zs = zc + plane_elems;                                   // +33.55 MB
    float2* partial = (float2*)((char*)d_ws + 2 * plane_elems * sizeof(ushort)); // +16.8 MB

    fft_analytic_kernel<<<BATCH * CHN, 256, 0, stream>>>(x, zc, zs);

    dim3 g2(BATCH, 2, NKCHUNK);
    gram_kernel<<<g2, 256, 0, stream>>>(zc, zs, partial);

    const int n_out = BATCH * CHN * CHN;
    reduce_kernel<<<(n_out + 255) / 256, 256, 0, stream>>>(partial, out);
}

// Round 3
// 232.774 us; speedup vs baseline: 3.2158x; 1.0113x over previous
//
#include <hip/hip_runtime.h>
#include <hip/hip_fp16.h>
#include <math.h>

#define T_LEN 8192
#define CHN 128
#define BATCH 16
#define NKCHUNK 16   // k-chunk = 512

typedef short bf16x8 __attribute__((ext_vector_type(8)));
typedef float f32x16 __attribute__((ext_vector_type(16)));

__device__ __forceinline__ ushort f2bf(float f) {
    unsigned u = __float_as_uint(f);
    unsigned r = (u + 0x7fffu + ((u >> 16) & 1u)) >> 16;
    return (ushort)r;
}

__device__ __forceinline__ float2 cadd(float2 a, float2 b) { return make_float2(a.x + b.x, a.y + b.y); }
__device__ __forceinline__ float2 csub(float2 a, float2 b) { return make_float2(a.x - b.x, a.y - b.y); }
__device__ __forceinline__ float2 cmul(float2 a, float2 b) {
    return make_float2(a.x * b.x - a.y * b.y, a.x * b.y + a.y * b.x);
}

// forward radix-4 DIF butterfly (verified round-2 code), twiddles wa=W, wb=W^2, wc=W^3
__device__ __forceinline__ void r4f(float2 x0, float2 x1, float2 x2, float2 x3,
                                    float2 wa, float2 wb, float2 wc,
                                    float2& y0, float2& y1, float2& y2, float2& y3) {
    float2 t0 = cadd(x0, x2), t1 = csub(x0, x2);
    float2 t2 = cadd(x1, x3), t3 = csub(x1, x3);
    y0 = cadd(t0, t2);
    y1 = cmul(csub(t0, t2), wb);
    y2 = cmul(make_float2(t1.x + t3.y, t1.y - t3.x), wa);
    y3 = cmul(make_float2(t1.x - t3.y, t1.y + t3.x), wc);
}

// inverse radix-4 DIT butterfly (verified round-2 code), twiddles wa=W, wb=W^2, wc=W^3 (W=e^{+i...})
__device__ __forceinline__ void r4i(float2 x0, float2 x1, float2 x2, float2 x3,
                                    float2 wa, float2 wb, float2 wc,
                                    float2& y0, float2& y1, float2& y2, float2& y3) {
    float2 a1 = cmul(x1, wb);
    float2 a2 = cmul(x2, wa);
    float2 a3 = cmul(x3, wc);
    float2 u0 = cadd(x0, a1), u1 = csub(x0, a1);
    float2 p = cadd(a2, a3);
    float2 m = make_float2(-(a2.y - a3.y), a2.x - a3.x);
    y0 = cadd(u0, p); y2 = csub(u0, p);
    y1 = cadd(u1, m); y3 = csub(u1, m);
}

// One block per (b,c) row: radix-8 FFT (4 passes) -> fused mask pass -> radix-8 IFFT (4 passes)
// -> normalize to unit modulus -> store cos/sin planes as bf16.  512 threads, 2 blocks/CU.
__global__ __launch_bounds__(512, 4) void fft_analytic_kernel(const float* __restrict__ x,
                                                              ushort* __restrict__ zc,
                                                              ushort* __restrict__ zs) {
    __shared__ __align__(16) float2 buf[T_LEN];   // 64 KiB
    const int tid = threadIdx.x;
    const size_t row = blockIdx.x;
    const float* xr = x + (row << 13);
    const float r22 = 0.70710678118654752f;

    for (int s = 0; s < 4; ++s) {
        int idx = tid + (s << 9);                 // float4 index, 2048 total
        float4 v = *(const float4*)(xr + idx * 4);
        *(float4*)&buf[idx * 4]     = make_float4(v.x, 0.f, v.y, 0.f);
        *(float4*)&buf[idx * 4 + 2] = make_float4(v.z, 0.f, v.w, 0.f);
    }
    __syncthreads();

    // forward radix-8 DIF: covers radix-2 distances 4096..2; natural -> digit-reversed
    for (int pq = 0; pq < 4; ++pq) {
        const int Q = 1024 >> (3 * pq);           // 1024,128,16,2
        const float astep = -(float)M_PI / (float)(4 * Q);
        for (int s = 0; s < 2; ++s) {
            const int g = tid + (s << 9);
            const int j = g & (Q - 1);
            const int i = ((g & ~(Q - 1)) << 3) | j;
            float2 x0 = buf[i],         x1 = buf[i + Q],     x2 = buf[i + 2 * Q], x3 = buf[i + 3 * Q];
            float2 x4 = buf[i + 4 * Q], x5 = buf[i + 5 * Q], x6 = buf[i + 6 * Q], x7 = buf[i + 7 * Q];
            float sn, cs;
            __sincosf(astep * (float)j, &sn, &cs);
            float2 w1 = make_float2(cs, sn);
            float2 w2 = make_float2(cs * cs - sn * sn, 2.f * cs * sn);
            float2 w4 = cmul(w2, w2);
            float2 w6 = cmul(w4, w2);
            // stage 4Q: u = a+b; v = (a-b)*w1*e^{-i pi k/4}
            float2 u0 = cadd(x0, x4), u1 = cadd(x1, x5), u2 = cadd(x2, x6), u3 = cadd(x3, x7);
            float2 e0 = cmul(csub(x0, x4), w1);
            float2 e1 = cmul(csub(x1, x5), w1);
            float2 e2 = cmul(csub(x2, x6), w1);
            float2 e3 = cmul(csub(x3, x7), w1);
            float2 v0 = e0;
            float2 v1 = make_float2(r22 * (e1.x + e1.y), r22 * (e1.y - e1.x));
            float2 v2 = make_float2(e2.y, -e2.x);
            float2 v3 = make_float2(r22 * (e3.y - e3.x), -r22 * (e3.x + e3.y));
            float2 y0, y1, y2, y3;
            r4f(u0, u1, u2, u3, w2, w4, w6, y0, y1, y2, y3);
            buf[i] = y0; buf[i + Q] = y1; buf[i + 2 * Q] = y2; buf[i + 3 * Q] = y3;
            r4f(v0, v1, v2, v3, w2, w4, w6, y0, y1, y2, y3);
            buf[i + 4 * Q] = y0; buf[i + 5 * Q] = y1; buf[i + 6 * Q] = y2; buf[i + 7 * Q] = y3;
        }
        __syncthreads();
    }

    // fused: fwd distance-1 stage + zero-odd-positions mask + inv distance-1 stage
    for (int s = 0; s < 8; ++s) {
        int q = tid + (s << 9);                   // pair index 0..4095
        float4 eo = *(const float4*)&buf[q * 2];
        float sx = eo.x + eo.z, sy = eo.y + eo.w;
        *(float4*)&buf[q * 2] = make_float4(sx, sy, sx, sy);
    }
    __syncthreads();

    // inverse radix-8 DIT: covers radix-2 distances 2..4096; digit-reversed -> natural
    for (int pq = 0; pq < 4; ++pq) {
        const int Q = 2 << (3 * pq);              // 2,16,128,1024
        const float astep = (float)M_PI / (float)(4 * Q);
        for (int s = 0; s < 2; ++s) {
            const int g = tid + (s << 9);
            const int j = g & (Q - 1);
            const int i = ((g & ~(Q - 1)) << 3) | j;
            float2 x0 = buf[i],         x1 = buf[i + Q],     x2 = buf[i + 2 * Q], x3 = buf[i + 3 * Q];
            float2 x4 = buf[i + 4 * Q], x5 = buf[i + 5 * Q], x6 = buf[i + 6 * Q], x7 = buf[i + 7 * Q];
            float sn, cs;
            __sincosf(astep * (float)j, &sn, &cs);
            float2 w1 = make_float2(cs, sn);
            float2 w2 = make_float2(cs * cs - sn * sn, 2.f * cs * sn);
            float2 w4 = cmul(w2, w2);
            float2 w6 = cmul(w4, w2);
            float2 y0, y1, y2, y3, y4, y5, y6, y7;
            r4i(x0, x1, x2, x3, w2, w4, w6, y0, y1, y2, y3);
            r4i(x4, x5, x6, x7, w2, w4, w6, y4, y5, y6, y7);
            // stage 4Q: t = y_{k+4}*w1*e^{+i pi k/4}
            float2 t0 = cmul(y4, w1);
            float2 e1 = cmul(y5, w1);
            float2 e2 = cmul(y6, w1);
            float2 e3 = cmul(y7, w1);
            float2 t1 = make_float2(r22 * (e1.x - e1.y), r22 * (e1.x + e1.y));
            float2 t2 = make_float2(-e2.y, e2.x);
            float2 t3 = make_float2(-r22 * (e3.x + e3.y), r22 * (e3.x - e3.y));
            buf[i]         = cadd(y0, t0); buf[i + 4 * Q] = csub(y0, t0);
            buf[i + Q]     = cadd(y1, t1); buf[i + 5 * Q] = csub(y1, t1);
            buf[i + 2 * Q] = cadd(y2, t2); buf[i + 6 * Q] = csub(y2, t2);
            buf[i + 3 * Q] = cadd(y3, t3); buf[i + 7 * Q] = csub(y3, t3);
        }
        __syncthreads();
    }

    // normalize to unit modulus: (cos(phase), sin(phase)); (0,0) -> (1,0)
    ushort* zcr = zc + (row << 13);
    ushort* zsr = zs + (row << 13);
    for (int s = 0; s < 8; ++s) {
        int tt = tid + (s << 9);                  // 0..4095, handles elements 2tt, 2tt+1
        float4 two = *(const float4*)&buf[tt * 2];
        float n0 = two.x * two.x + two.y * two.y;
        float n1 = two.z * two.z + two.w * two.w;
        float c0 = 1.f, s0 = 0.f, c1 = 1.f, s1 = 0.f;
        if (n0 > 0.f) { float inv = rsqrtf(n0); c0 = two.x * inv; s0 = two.y * inv; }
        if (n1 > 0.f) { float inv = rsqrtf(n1); c1 = two.z * inv; s1 = two.w * inv; }
        *(ushort2*)&zcr[tt * 2] = make_ushort2(f2bf(c0), f2bf(c1));
        *(ushort2*)&zsr[tt * 2] = make_ushort2(f2bf(s0), f2bf(s1));
    }
}

// MFMA Gram partials. grid=(BATCH, 2 col-halves, NKCHUNK), block=256 (4 waves).
// Block computes G[b][0:128][j0:j0+64] over t-chunk of 512, register-double-buffered staging.
__global__ __launch_bounds__(256) void gram_kernel(const ushort* __restrict__ zc,
                                                   const ushort* __restrict__ zs,
                                                   __half2* __restrict__ partial) {
    const int b = blockIdx.x, jh = blockIdx.y, kc = blockIdx.z;
    const int j0 = jh * 64;
    const int tid = threadIdx.x;
    const int wave = tid >> 6;
    const int lane31 = tid & 31;
    const int half = (tid >> 5) & 1;

    __shared__ __align__(16) ushort sZ[2 * 128 * 40];   // C plane then S plane, stride 40

    f32x16 accRe[2], accIm[2];
#pragma unroll
    for (int v = 0; v < 2; ++v)
#pragma unroll
        for (int r = 0; r < 16; ++r) { accRe[v][r] = 0.f; accIm[v][r] = 0.f; }

    const size_t base = ((size_t)b * CHN) << 13;
    const int k0 = kc << 9;   // *512

    const ushort* srcs[4];
    int ldst[4];
#pragma unroll
    for (int q = 0; q < 4; ++q) {
        int id = tid + (q << 8);                   // 0..1023
        int plane = id >> 9;
        int rid = (id >> 2) & 127;
        int ck = id & 3;
        srcs[q] = (plane ? zs : zc) + base + ((size_t)rid << 13) + (size_t)(k0 + ck * 8);
        ldst[q] = plane * (128 * 40) + rid * 40 + ck * 8;
    }

    uint4 pre[4];
#pragma unroll
    for (int q = 0; q < 4; ++q) pre[q] = *(const uint4*)srcs[q];

    for (int it = 0; it < 16; ++it) {
        __syncthreads();
#pragma unroll
        for (int q = 0; q < 4; ++q) *(uint4*)&sZ[ldst[q]] = pre[q];
        __syncthreads();
        if (it < 15) {
#pragma unroll
            for (int q = 0; q < 4; ++q) pre[q] = *(const uint4*)(srcs[q] + (it + 1) * 32);
        }
#pragma unroll
        for (int kb = 0; kb < 32; kb += 16) {
            const int aoff = (wave * 32 + lane31) * 40 + kb + half * 8;
            bf16x8 aC = *(const bf16x8*)&sZ[aoff];
            bf16x8 aS = *(const bf16x8*)&sZ[128 * 40 + aoff];
            bf16x8 aCn;
#pragma unroll
            for (int r = 0; r < 8; ++r) aCn[r] = (short)(aC[r] ^ (short)0x8000);
#pragma unroll
            for (int v = 0; v < 2; ++v) {
                const int boff = (j0 + v * 32 + lane31) * 40 + kb + half * 8;
                bf16x8 bC = *(const bf16x8*)&sZ[boff];
                bf16x8 bS = *(const bf16x8*)&sZ[128 * 40 + boff];
                accRe[v] = __builtin_amdgcn_mfma_f32_32x32x16_bf16(aC,  bC, accRe[v], 0, 0, 0);
                accRe[v] = __builtin_amdgcn_mfma_f32_32x32x16_bf16(aS,  bS, accRe[v], 0, 0, 0);
                accIm[v] = __builtin_amdgcn_mfma_f32_32x32x16_bf16(aS,  bC, accIm[v], 0, 0, 0);
                accIm[v] = __builtin_amdgcn_mfma_f32_32x32x16_bf16(aCn, bS, accIm[v], 0, 0, 0);
            }
        }
    }

    // C/D layout (verified m74/m101): col=lane&31, row=(reg&3)+8*(reg>>2)+4*(lane>>5)
    __half2* pb = partial + ((size_t)(kc * BATCH + b) << 14);
#pragma unroll
    for (int v = 0; v < 2; ++v)
#pragma unroll
        for (int r = 0; r < 16; ++r) {
            int rrow = (r & 3) + 8 * (r >> 2) + 4 * half;
            int i = wave * 32 + rrow;
            int j = j0 + v * 32 + lane31;
            pb[i * CHN + j] = __floats2half2_rn(accRe[v][r], accIm[v][r]);
        }
}

__global__ __launch_bounds__(256) void reduce_kernel(const __half2* __restrict__ partial,
                                                     float* __restrict__ out) {
    const size_t i = (size_t)blockIdx.x * 256 + threadIdx.x;
    const size_t n = (size_t)BATCH * CHN * CHN;
    if (i >= n) return;
    float re = 0.0f, im = 0.0f;
#pragma unroll
    for (int c = 0; c < NKCHUNK; ++c) {
        float2 p = __half22float2(partial[(size_t)c * n + i]);
        re += p.x;
        im += p.y;
    }
    out[i] = sqrtf(re * re + im * im) * (1.0f / (float)T_LEN);
}

extern "C" void kernel_launch(void* const* d_in, const int* in_sizes, int n_in,
                              void* d_out, int out_size, void* d_ws, size_t ws_size,
                              hipStream_t stream) {
    const float* x = (const float*)d_in[0];
    float* out = (float*)d_out;

    const size_t plane_elems = (size_t)BATCH * CHN * T_LEN;                 // 16.8M
    ushort* zc = (ushort*)d_ws;                                             // 33.55 MB
    ushort* zs = zc + plane_elems;                                          // +33.55 MB
    __half2* partial = (__half2*)((char*)d_ws + 2 * plane_elems * sizeof(ushort)); // +16.78 MB

    fft_analytic_kernel<<<BATCH * CHN, 512, 0, stream>>>(x, zc, zs);

    dim3 g2(BATCH, 2, NKCHUNK);
    gram_kernel<<<g2, 256, 0, stream>>>(zc, zs, partial);

    const int n_out = BATCH * CHN * CHN;
    reduce_kernel<<<(n_out + 255) / 256, 256, 0, stream>>>(partial, out);
}